// Round 11
// baseline (655.471 us; speedup 1.0000x reference)
//
#include <hip/hip_runtime.h>
#include <math.h>

#define LMAXX 6
#define TPB 256
#define TILE_E 64
#define SCB 256
#define CAPS 12   // max distinct nodes per tile for LDS slot path

typedef __attribute__((ext_vector_type(8))) short short8v;
typedef __attribute__((ext_vector_type(16))) float f32x16;
union FragU { short8v v; uint2 u2[2]; uint4 u4; };

// ---------------------------------------------------------------------------
// bf16 pack/unpack helpers (RNE)
// ---------------------------------------------------------------------------
__device__ __forceinline__ unsigned pack_bf16(float a, float b) {
    unsigned ua = __float_as_uint(a);
    unsigned ub = __float_as_uint(b);
    ua += 0x7fffu + ((ua >> 16) & 1u);
    ub += 0x7fffu + ((ub >> 16) & 1u);
    return (ua >> 16) | (ub & 0xffff0000u);
}
__device__ __forceinline__ float bf16_lo(unsigned w) { return __uint_as_float(w << 16); }
__device__ __forceinline__ float bf16_hi(unsigned w) { return __uint_as_float(w & 0xffff0000u); }

// ---------------------------------------------------------------------------
// Direction -> (z, sin_theta, cos_phi, sin_phi), matching reference sph_harm.
// ---------------------------------------------------------------------------
__device__ __forceinline__ void dirang(float x, float y, float z,
                                       float& zo, float& st, float& cphi, float& sphi) {
    float nn = sqrtf(x * x + y * y + z * z + 1e-12f);
    float iv = 1.0f / nn;
    x *= iv; y *= iv; zo = z * iv;
    float st2 = x * x + y * y;
    st = sqrtf(st2 > 0.f ? st2 : 0.f);
    if (st > 1e-30f) { cphi = x / st; sphi = y / st; }
    else { cphi = 1.0f; sphi = 0.0f; }
}

// Associated Legendre table (component normalization, as in reference).
__device__ __forceinline__ void legP(float z, float st, float P[7][7]) {
    P[0][0] = 0.28209479177387814f;
#pragma unroll
    for (int m = 1; m <= LMAXX; ++m)
        P[m][m] = -sqrtf((2.f * m + 1.f) / (2.f * m)) * st * P[m - 1][m - 1];
#pragma unroll
    for (int m = 0; m < LMAXX; ++m)
        P[m + 1][m] = sqrtf(2.f * m + 3.f) * z * P[m][m];
#pragma unroll
    for (int m = 0; m <= LMAXX; ++m) {
#pragma unroll
        for (int l = m + 2; l <= LMAXX; ++l) {
            float a = sqrtf((4.f * l * l - 1.f) / (float)(l * l - m * m));
            float b = sqrtf((float)((l - 1) * (l - 1) - m * m) /
                            (4.f * (l - 1) * (l - 1) - 1.f));
            P[l][m] = a * (z * P[l - 1][m] - b * P[l - 2][m]);
        }
    }
}

// ---------------------------------------------------------------------------
// K1: destination-degree histogram (int atomics only).
// ---------------------------------------------------------------------------
__global__ void k_hist(const int* __restrict__ eidx, int* __restrict__ icnt, int E) {
    int e = blockIdx.x * blockDim.x + threadIdx.x;
    if (e >= E) return;
    atomicAdd(&icnt[eidx[E + e]], 1);
}

// ---------------------------------------------------------------------------
// Counting-sort scan kernels: exclusive prefix over icnt[N].
// ---------------------------------------------------------------------------
__global__ void k_scan1(const int* __restrict__ icnt, int* __restrict__ offs,
                        int* __restrict__ bsum, int N) {
    __shared__ int s[SCB];
    int t = threadIdx.x;
    int idx = blockIdx.x * SCB + t;
    int v = (idx < N) ? icnt[idx] : 0;
    s[t] = v; __syncthreads();
#pragma unroll
    for (int off = 1; off < SCB; off <<= 1) {
        int u = (t >= off) ? s[t - off] : 0;
        __syncthreads();
        s[t] += u;
        __syncthreads();
    }
    if (idx < N) offs[idx] = s[t] - v;
    if (t == SCB - 1) bsum[blockIdx.x] = s[t];
}

__global__ void k_scan2(int* __restrict__ bsum, int nb) {
    __shared__ int s[1024];
    int t = threadIdx.x;
    int v = (t < nb) ? bsum[t] : 0;
    s[t] = v; __syncthreads();
#pragma unroll
    for (int off = 1; off < 1024; off <<= 1) {
        int u = (t >= off) ? s[t - off] : 0;
        __syncthreads();
        s[t] += u;
        __syncthreads();
    }
    if (t < nb) bsum[t] = s[t] - v;
}

__global__ void k_scan3(int* __restrict__ offs, const int* __restrict__ bsum,
                        int* __restrict__ cursor, int N) {
    int idx = blockIdx.x * SCB + threadIdx.x;
    if (idx >= N) return;
    int o = offs[idx] + bsum[blockIdx.x];
    offs[idx] = o;
    cursor[idx] = o;
}

// ---------------------------------------------------------------------------
// K2: build sorted AoS edge struct. estr[pos] = 2 x uint4:
//   lo = {i, perm(orig e), 0, 0}
//   hi = {j, udx, udy, udz}
// One scattered 32B region per edge (1 cacheline) instead of 4 arrays.
// ---------------------------------------------------------------------------
__global__ void k_perm(const float* __restrict__ ud, const int* __restrict__ eidx,
                       int* __restrict__ cursor, uint4* __restrict__ estr, int E) {
    int e = blockIdx.x * blockDim.x + threadIdx.x;
    if (e >= E) return;
    int i = eidx[E + e];
    int j = eidx[e];
    int pos = atomicAdd(&cursor[i], 1);
    estr[2 * pos]     = make_uint4((unsigned)i, (unsigned)e, 0u, 0u);
    estr[2 * pos + 1] = make_uint4((unsigned)j, __float_as_uint(ud[3 * e + 0]),
                                   __float_as_uint(ud[3 * e + 1]),
                                   __float_as_uint(ud[3 * e + 2]));
}

// ---------------------------------------------------------------------------
// K3: per-node ref_vec via CSR segment sum (no atomics).
// ---------------------------------------------------------------------------
__global__ void k_node_ref(const int* __restrict__ offs, const int* __restrict__ icnt,
                           const uint4* __restrict__ estr,
                           float* __restrict__ ref_vec, int N) {
    int n = blockIdx.x * blockDim.x + threadIdx.x;
    if (n >= N) return;
    int o0 = offs[n], c = icnt[n];
    float sx = 0.f, sy = 0.f, sz = 0.f;
    for (int e = o0; e < o0 + c; ++e) {
        uint4 hi = estr[2 * e + 1];
        sx += __uint_as_float(hi.y);
        sy += __uint_as_float(hi.z);
        sz += __uint_as_float(hi.w);
    }
    float d = fmaxf((float)c, 1.0f);
    float vx = sx / d, vy = sy / d, vz = sz / d;
    float norm = sqrtf(vx * vx + vy * vy + vz * vz + 1e-9f);
    float ivn = 1.0f / norm;
    vx *= ivn; vy *= ivn; vz *= ivn;
    if (norm < 5e-5f) { vx = 1.f; vy = 0.f; vz = 0.f; }
    ref_vec[3 * n + 0] = vx;
    ref_vec[3 * n + 1] = vy;
    ref_vec[3 * n + 2] = vz;
}

// ---------------------------------------------------------------------------
// K4: fused scalar_proj + node_vector pack -> combined gather array.
// gat[n][plane][h], h=0..63:
//   plane0[h] = (sp_h,     sp_{64+h})
//   plane1[h] = (sp_{128+h}, nv_h)
//   plane2[h] = (nv_{64+h}, nv_{128+h})
// ---------------------------------------------------------------------------
__global__ __launch_bounds__(TPB) void k_sprojv(const float* __restrict__ ns,
                                                const float* __restrict__ W1,
                                                const float* __restrict__ b1,
                                                const float* __restrict__ W2,
                                                const float* __restrict__ b2,
                                                const float* __restrict__ nvec,
                                                unsigned* __restrict__ gat, int N) {
    __shared__ float sW1[64 * 32];
    __shared__ float sW2[32 * 192];
    __shared__ float sb2[192];
    __shared__ float sb1[32];
    __shared__ float sbuf[4][64];
    __shared__ float h1buf[4][32];
    int t = threadIdx.x;
    for (int p = t; p < 64 * 32; p += TPB) sW1[p] = W1[p];
    for (int p = t; p < 32 * 192; p += TPB) sW2[p] = W2[p];
    if (t < 192) sb2[t] = b2[t];
    if (t < 32) sb1[t] = b1[t];

    int w = t >> 6, l = t & 63;
    int nwaves = gridDim.x * 4;
    int iters = (N + nwaves - 1) / nwaves;
    for (int it = 0; it < iters; ++it) {
        int n = blockIdx.x * 4 + w + it * nwaves;
        bool act = n < N;
        __syncthreads();
        if (act) sbuf[w][l] = ns[(size_t)n * 64 + l];
        __syncthreads();
        if (act) {
            int k = l & 31;
            float h = sb1[k];
#pragma unroll
            for (int c = 0; c < 64; ++c) h = fmaf(sbuf[w][c], sW1[c * 32 + k], h);
            float sig = 1.0f / (1.0f + __expf(-h));
            h = h * sig * (1.0f / 0.6f);
            if (l < 32) h1buf[w][l] = h;
        }
        __syncthreads();
        if (act) {
            float a[3];
#pragma unroll
            for (int m = 0; m < 3; ++m) {
                int o = l + 64 * m;
                float acc = sb2[o];
#pragma unroll
                for (int kk = 0; kk < 32; ++kk)
                    acc = fmaf(h1buf[w][kk], sW2[kk * 192 + o], acc);
                a[m] = acc;
            }
            size_t nb = (size_t)n * 192;
            float nv0 = nvec[nb + l];
            float nv1 = nvec[nb + 64 + l];
            float nv2 = nvec[nb + 128 + l];
            gat[nb + l]        = pack_bf16(a[0], a[1]);
            gat[nb + 64 + l]   = pack_bf16(a[2], nv0);
            gat[nb + 128 + l]  = pack_bf16(nv1, nv2);
        }
    }
}

// ---------------------------------------------------------------------------
// K5: pack W_inv (8x192) -> bf16 k-pair B operand, K padded to 16.
// ---------------------------------------------------------------------------
__global__ void k_wpk(const float* __restrict__ W_inv, unsigned* __restrict__ wpk) {
    int idx = blockIdx.x * blockDim.x + threadIdx.x;
    if (idx >= 192 * 8) return;
    int col = idx >> 3, p = idx & 7;
    unsigned v = 0u;
    if (p < 4)
        v = pack_bf16(W_inv[(2 * p) * 192 + col], W_inv[(2 * p + 1) * 192 + col]);
    wpk[col * 8 + p] = v;
}

// ---------------------------------------------------------------------------
// K6: geometry features in sorted order -> bf16-packed geom16 [edge][8 dwords]
// (k-pairs (g0,g1)..(g6,g7), then 4 zero dwords = K padding to 16).
// g = [cos_theta, LN(inv)_0..6]. Ref-SH inline via lockstep Legendre product.
// ---------------------------------------------------------------------------
__global__ void k_geom_s(const uint4* __restrict__ estr,
                         const float* __restrict__ ref_vec,
                         const float* __restrict__ ln_g, const float* __restrict__ ln_b,
                         uint4* __restrict__ geom16, int E) {
    int r = blockIdx.x * blockDim.x + threadIdx.x;
    if (r >= E) return;
    uint4 lo = estr[2 * (size_t)r];
    uint4 hi = estr[2 * (size_t)r + 1];
    int i = (int)lo.x;
    float ux = __uint_as_float(hi.y);
    float uy = __uint_as_float(hi.z);
    float uz = __uint_as_float(hi.w);
    float rvx = ref_vec[3 * i], rvy = ref_vec[3 * i + 1], rvz = ref_vec[3 * i + 2];

    float zE, stE, cpE, spE, zR, stR, cpR, spR;
    dirang(ux, uy, uz, zE, stE, cpE, spE);
    dirang(rvx, rvy, rvz, zR, stR, cpR, spR);

    float Pe[7][7], Pr[7][7];
    legP(zE, stE, Pe);
    legP(zR, stR, Pr);

    float cmE[7], smE[7], cmR[7], smR[7];
    cmE[0] = 1.f; smE[0] = 0.f; cmE[1] = cpE; smE[1] = spE;
    cmR[0] = 1.f; smR[0] = 0.f; cmR[1] = cpR; smR[1] = spR;
#pragma unroll
    for (int m = 2; m <= LMAXX; ++m) {
        cmE[m] = 2.f * cpE * cmE[m - 1] - cmE[m - 2];
        smE[m] = 2.f * cpE * smE[m - 1] - smE[m - 2];
        cmR[m] = 2.f * cpR * cmR[m - 1] - cmR[m - 2];
        smR[m] = 2.f * cpR * smR[m - 1] - smR[m - 2];
    }

    float inv[7];
#pragma unroll
    for (int l = 0; l <= LMAXX; ++l) inv[l] = Pe[l][0] * Pr[l][0];
#pragma unroll
    for (int m = 1; m <= LMAXX; ++m) {
        float cross = cmE[m] * cmR[m] + smE[m] * smR[m];
#pragma unroll
        for (int l = m; l <= LMAXX; ++l)
            inv[l] += 2.f * Pe[l][m] * Pr[l][m] * cross;
    }
    const float fourpi = 12.566370614359172f;
#pragma unroll
    for (int l = 0; l <= LMAXX; ++l) inv[l] *= fourpi / (float)(2 * l + 1);

    float mu = 0.f;
#pragma unroll
    for (int l = 0; l < 7; ++l) mu += inv[l];
    mu *= (1.0f / 7.0f);
    float var = 0.f;
#pragma unroll
    for (int l = 0; l < 7; ++l) { float d = inv[l] - mu; var += d * d; }
    var *= (1.0f / 7.0f);
    float rstd = rsqrtf(var + 1e-5f);
    float ct = ux * rvx + uy * rvy + uz * rvz;
    float g[8];
    g[0] = ct;
#pragma unroll
    for (int l = 0; l < 7; ++l) g[1 + l] = (inv[l] - mu) * rstd * ln_g[l] + ln_b[l];
    geom16[2 * (size_t)r] = make_uint4(pack_bf16(g[0], g[1]), pack_bf16(g[2], g[3]),
                                       pack_bf16(g[4], g[5]), pack_bf16(g[6], g[7]));
    geom16[2 * (size_t)r + 1] = make_uint4(0u, 0u, 0u, 0u);
}

// ---------------------------------------------------------------------------
// K7: fused main kernel. Both GEMMs on MFMA:
//   phase 1: u = geom16 @ W_inv16 + b_inv (3x mfma, C init = bias splat)
//            -> immediately collapsed to bf16 gate factors gf (24 VGPRs)
//   phase 2: rbf_h = rbf @ W_edge         (12x mfma, acc 48 VGPRs)
// Identical C/D layouts -> row r of ugate aligns with row r of acc.
// ---------------------------------------------------------------------------
__global__ __launch_bounds__(TPB, 4) void k_main(
    const float* __restrict__ rbf, const float* __restrict__ W_edge,
    const float* __restrict__ b_edge, const float* __restrict__ b_inv,
    const unsigned* __restrict__ wpk, const uint4* __restrict__ geom16,
    const unsigned* __restrict__ gat, const uint4* __restrict__ estr,
    float* __restrict__ dscal, float* __restrict__ dvec, int E) {
    __shared__ __align__(16) unsigned sWT[192 * 34];  // 25.5 KB W^T bf16 pairs [col][k/2]
    __shared__ int sii[64];
    __shared__ int sslot[64];
    __shared__ int sfirst[64];
    __shared__ int sD;
    __shared__ float sacc[CAPS * 256];                // 12 KB slot accumulators

    int t = threadIdx.x;
    int l = t & 63;
    int wid = t >> 6;
    int eh = wid >> 1;        // edge half 0/1
    int wc = wid & 1;         // col pair 0/1
    int lo5 = l & 31;
    int hi = l >> 5;
    int h = wc * 32 + lo5;    // this lane's column triple: h, 64+h, 128+h

    for (int p = t; p < 192 * 32; p += TPB) {
        int col = p >> 5, kd = p & 31;
        sWT[col * 34 + kd] = pack_bf16(W_edge[(2 * kd) * 192 + col],
                                       W_edge[(2 * kd + 1) * 192 + col]);
    }

    FragU bwi[3];
#pragma unroll
    for (int q = 0; q < 3; ++q)
        bwi[q].u4 = *(const uint4*)&wpk[(q * 64 + h) * 8 + hi * 4];
    float bi[3], be[3];
#pragma unroll
    for (int q = 0; q < 3; ++q) {
        bi[q] = b_inv[q * 64 + h];
        be[q] = b_edge[q * 64 + h];
    }

    const float inv_sqrt3 = 0.57735026918962584f;
    const float inv_sqrt_h = 0.125f;

    int ntiles = (E + TILE_E - 1) / TILE_E;
    for (int tile = blockIdx.x; tile < ntiles; tile += gridDim.x) {
        int e0 = tile * TILE_E;
        __syncthreads();   // (A)
        if (t < 64) {
            int rg = e0 + t;
            sii[t] = (rg < E) ? (int)estr[2 * (size_t)rg].x : -1;
        }
        __syncthreads();   // (B)

        if (t < 64) {
            bool flag = (t == 0) || (sii[t] != sii[t - 1]);
            unsigned long long bal = __ballot(flag);
            unsigned long long mask =
                (t == 63) ? ~0ull : ((1ull << (t + 1)) - 1ull);
            int slot = __popcll(bal & mask) - 1;
            sslot[t] = slot;
            if (flag) sfirst[slot] = t;
            if (t == 0) sD = __popcll(bal);
        }

        int arow = lo5 + 32 * eh;
        int rga = e0 + arow;

        // ---- phase 1: gate factors via MFMA, collapsed to bf16 ----
        unsigned gf[3][8];
        {
            FragU ga;
            if (rga < E) ga.u4 = ((const uint4*)&geom16[2 * (size_t)rga])[hi];
            else         ga.u4 = make_uint4(0u, 0u, 0u, 0u);
            f32x16 ug0, ug1, ug2;
#pragma unroll
            for (int r = 0; r < 16; ++r) { ug0[r] = bi[0]; ug1[r] = bi[1]; ug2[r] = bi[2]; }
            ug0 = __builtin_amdgcn_mfma_f32_32x32x16_bf16(ga.v, bwi[0].v, ug0, 0, 0, 0);
            ug1 = __builtin_amdgcn_mfma_f32_32x32x16_bf16(ga.v, bwi[1].v, ug1, 0, 0, 0);
            ug2 = __builtin_amdgcn_mfma_f32_32x32x16_bf16(ga.v, bwi[2].v, ug2, 0, 0, 0);
            auto gfac = [&](float u) -> float {
                float sig = 1.0f / (1.0f + __expf(-u));
                float v = u * sig * (1.0f / 0.6f);
                v = fminf(fmaxf(v, -20.f), 20.f);
                float e2v = __expf(2.0f * v);
                float gate = (e2v - 1.0f) / (e2v + 1.0f);
                return (1.0f + gate) * inv_sqrt3;
            };
#pragma unroll
            for (int rp = 0; rp < 8; ++rp) {
                gf[0][rp] = pack_bf16(gfac(ug0[2 * rp]), gfac(ug0[2 * rp + 1]));
                gf[1][rp] = pack_bf16(gfac(ug1[2 * rp]), gfac(ug1[2 * rp + 1]));
                gf[2][rp] = pack_bf16(gfac(ug2[2 * rp]), gfac(ug2[2 * rp + 1]));
            }
        }

        // ---- phase 2: main GEMM ----
        FragU afr[4];
        if (rga < E) {
            int row = (int)estr[2 * (size_t)rga].y;
            const float4* rp = (const float4*)&rbf[(size_t)row * 64 + hi * 8];
#pragma unroll
            for (int ks = 0; ks < 4; ++ks) {
                float4 f0 = rp[ks * 4];
                float4 f1 = rp[ks * 4 + 1];
                afr[ks].u2[0] = make_uint2(pack_bf16(f0.x, f0.y), pack_bf16(f0.z, f0.w));
                afr[ks].u2[1] = make_uint2(pack_bf16(f1.x, f1.y), pack_bf16(f1.z, f1.w));
            }
        } else {
#pragma unroll
            for (int ks = 0; ks < 4; ++ks) {
                afr[ks].u2[0] = make_uint2(0u, 0u);
                afr[ks].u2[1] = make_uint2(0u, 0u);
            }
        }

        f32x16 acc0 = {0.f,0.f,0.f,0.f,0.f,0.f,0.f,0.f,0.f,0.f,0.f,0.f,0.f,0.f,0.f,0.f};
        f32x16 acc1 = acc0, acc2 = acc0;
        int bc0 = (wc * 32 + lo5) * 34;
#pragma unroll
        for (int ks = 0; ks < 4; ++ks) {
            int off = ks * 8 + hi * 4;
            FragU b0, b1, b2;
            b0.u2[0] = *(const uint2*)&sWT[bc0 + off];
            b0.u2[1] = *(const uint2*)&sWT[bc0 + off + 2];
            b1.u2[0] = *(const uint2*)&sWT[bc0 + 64 * 34 + off];
            b1.u2[1] = *(const uint2*)&sWT[bc0 + 64 * 34 + off + 2];
            b2.u2[0] = *(const uint2*)&sWT[bc0 + 128 * 34 + off];
            b2.u2[1] = *(const uint2*)&sWT[bc0 + 128 * 34 + off + 2];
            acc0 = __builtin_amdgcn_mfma_f32_32x32x16_bf16(afr[ks].v, b0.v, acc0, 0, 0, 0);
            acc1 = __builtin_amdgcn_mfma_f32_32x32x16_bf16(afr[ks].v, b1.v, acc1, 0, 0, 0);
            acc2 = __builtin_amdgcn_mfma_f32_32x32x16_bf16(afr[ks].v, b2.v, acc2, 0, 0, 0);
        }

        __syncthreads();   // (C)
        int D = sD;
        bool slotmode = (D <= CAPS);
        if (slotmode) {
            for (int p = t; p < D * 256; p += TPB) sacc[p] = 0.f;
        }
        __syncthreads();   // (D)

        float a_s = 0.f, a_v0 = 0.f, a_v1 = 0.f, a_v2 = 0.f;
        int runi = -1, runslot = -1;
        auto flush = [&]() {
            if (runi < 0) return;
            if (slotmode) {
                float* sa = &sacc[runslot * 256];
                atomicAdd(&sa[h], a_s);
                atomicAdd(&sa[64 + h], a_v0);
                atomicAdd(&sa[128 + h], a_v1);
                atomicAdd(&sa[192 + h], a_v2);
            } else {
                atomicAdd(&dscal[(size_t)runi * 64 + h], a_s);
                atomicAdd(&dvec[(size_t)runi * 192 + h], a_v0);
                atomicAdd(&dvec[(size_t)runi * 192 + 64 + h], a_v1);
                atomicAdd(&dvec[(size_t)runi * 192 + 128 + h], a_v2);
            }
        };
#pragma unroll
        for (int r = 0; r < 16; ++r) {
            int el = eh * 32 + (r & 3) + 8 * (r >> 2) + 4 * hi;
            int rg = e0 + el;
            if (rg < E) {
                int i = sii[el];
                if (i != runi) {
                    flush();
                    a_s = 0.f; a_v0 = 0.f; a_v1 = 0.f; a_v2 = 0.f;
                    runi = i; runslot = sslot[el];
                }
                uint4 eh4 = estr[2 * (size_t)rg + 1];   // {j, udx, udy, udz}
                int j = (int)eh4.x;
                size_t jb = (size_t)j * 192;
                unsigned w0 = gat[jb + h];
                unsigned w1 = gat[jb + 64 + h];
                unsigned w2 = gat[jb + 128 + h];
                float sp0 = bf16_lo(w0), sp1 = bf16_hi(w0), sp2 = bf16_lo(w1);
                float nv0 = bf16_hi(w1), nv1 = bf16_lo(w2), nv2 = bf16_hi(w2);
                float gf0 = (r & 1) ? bf16_hi(gf[0][r >> 1]) : bf16_lo(gf[0][r >> 1]);
                float gf1 = (r & 1) ? bf16_hi(gf[1][r >> 1]) : bf16_lo(gf[1][r >> 1]);
                float gf2 = (r & 1) ? bf16_hi(gf[2][r >> 1]) : bf16_lo(gf[2][r >> 1]);
                float x1 = sp0 * (acc0[r] + be[0]) * gf0;
                float x2 = sp1 * (acc1[r] + be[1]) * gf1;
                float x3 = sp2 * (acc2[r] + be[2]) * gf2;
                a_s += x3;
                float ud0 = __uint_as_float(eh4.y);
                float ud1 = __uint_as_float(eh4.z);
                float ud2 = __uint_as_float(eh4.w);
                a_v0 += (x1 * nv0 + x2 * ud0) * inv_sqrt_h;
                a_v1 += (x1 * nv1 + x2 * ud1) * inv_sqrt_h;
                a_v2 += (x1 * nv2 + x2 * ud2) * inv_sqrt_h;
            }
        }
        flush();
        __syncthreads();   // (E)

        if (slotmode) {
            int Dreal = D - ((sii[63] < 0) ? 1 : 0);
            for (int s = 0; s < D; ++s) {
                int n = sii[sfirst[s]];
                if (n < 0) continue;
                float val = sacc[s * 256 + t];
                bool boundary = (s == 0) || (s == Dreal - 1);
                float* ptr = (t < 64) ? &dscal[(size_t)n * 64 + t]
                                      : &dvec[(size_t)n * 192 + (t - 64)];
                if (boundary) atomicAdd(ptr, val);
                else *ptr = val;
            }
        }
    }
}

// ---------------------------------------------------------------------------
extern "C" void kernel_launch(void* const* d_in, const int* in_sizes, int n_in,
                              void* d_out, int out_size, void* d_ws, size_t ws_size,
                              hipStream_t stream) {
    const float* node_scalar = (const float*)d_in[0];
    const float* node_vector = (const float*)d_in[1];
    const float* edge_rbf    = (const float*)d_in[2];
    const float* edge_udiff  = (const float*)d_in[3];
    const int*   edge_index  = (const int*)d_in[4];
    const float* W_edge      = (const float*)d_in[5];
    const float* b_edge      = (const float*)d_in[6];
    const float* W_x1        = (const float*)d_in[7];
    const float* b_x1        = (const float*)d_in[8];
    const float* W_x2        = (const float*)d_in[9];
    const float* b_x2        = (const float*)d_in[10];
    const float* ln_g        = (const float*)d_in[11];
    const float* ln_b        = (const float*)d_in[12];
    const float* W_inv       = (const float*)d_in[13];
    const float* b_inv       = (const float*)d_in[14];

    int N = in_sizes[0] / 64;
    int E = in_sizes[3] / 3;

    float* ws = (float*)d_ws;
    size_t o = 0;
    auto A8 = [&]() { o = (o + 7) & ~(size_t)7; };
    int*      icnt   = (int*)(ws + o); o += N; A8();
    int*      offs   = (int*)(ws + o); o += N; A8();
    int*      cursor = (int*)(ws + o); o += N; A8();
    int*      bsum   = (int*)(ws + o); o += 1024; A8();
    float*    ref_vec= ws + o; o += (size_t)N * 3; A8();
    unsigned* gat    = (unsigned*)(ws + o); o += (size_t)N * 192; A8();
    unsigned* wpk    = (unsigned*)(ws + o); o += 192 * 8; A8();
    uint4*    estr   = (uint4*)(ws + o); o += (size_t)E * 8; A8();
    uint4*    geom16 = (uint4*)(ws + o); o += (size_t)E * 8; A8();

    float* dscal = (float*)d_out;                       // N*64
    float* dvec  = (float*)d_out + (size_t)N * 64;      // N*192

    hipMemsetAsync(icnt, 0, (size_t)N * sizeof(int), stream);
    hipMemsetAsync(d_out, 0, (size_t)out_size * sizeof(float), stream);

    int nb = (N + SCB - 1) / SCB;

    k_hist<<<(E + TPB - 1) / TPB, TPB, 0, stream>>>(edge_index, icnt, E);
    k_scan1<<<nb, SCB, 0, stream>>>(icnt, offs, bsum, N);
    k_scan2<<<1, 1024, 0, stream>>>(bsum, nb);
    k_scan3<<<nb, SCB, 0, stream>>>(offs, bsum, cursor, N);
    k_perm<<<(E + TPB - 1) / TPB, TPB, 0, stream>>>(edge_udiff, edge_index, cursor,
                                                    estr, E);
    k_node_ref<<<(N + TPB - 1) / TPB, TPB, 0, stream>>>(offs, icnt, estr, ref_vec, N);
    k_sprojv<<<512, TPB, 0, stream>>>(node_scalar, W_x1, b_x1, W_x2, b_x2,
                                      node_vector, gat, N);
    k_wpk<<<(192 * 8 + TPB - 1) / TPB, TPB, 0, stream>>>(W_inv, wpk);
    k_geom_s<<<(E + TPB - 1) / TPB, TPB, 0, stream>>>(estr, ref_vec, ln_g, ln_b,
                                                      geom16, E);
    k_main<<<1024, TPB, 0, stream>>>(edge_rbf, W_edge, b_edge, b_inv, wpk, geom16,
                                     gat, estr, dscal, dvec, E);
}